// Round 2
// baseline (546.822 us; speedup 1.0000x reference)
//
#include <hip/hip_runtime.h>
#include <hip/hip_bf16.h>

#define B_  2
#define S_  2048
#define D_  2048
#define H_  16
#define DH_ 128

typedef __attribute__((ext_vector_type(8))) short bf16x8;
typedef __attribute__((ext_vector_type(4))) float f32x4;

__device__ inline short bf16bits(float v) {
    __hip_bfloat16 h = __float2bfloat16(v);
    return *reinterpret_cast<short*>(&h);
}

// ---------------------------------------------------------------------------
// fp32 -> bf16 cast, 8 elements/thread.
// ---------------------------------------------------------------------------
__global__ __launch_bounds__(256)
void f2b_kernel(const float* __restrict__ in, __hip_bfloat16* __restrict__ out)
{
    const size_t i = ((size_t)blockIdx.x * 256 + threadIdx.x) * 8;
    float4 a = *(const float4*)(in + i);
    float4 b = *(const float4*)(in + i + 4);
    short s[8] = { bf16bits(a.x), bf16bits(a.y), bf16bits(a.z), bf16bits(a.w),
                   bf16bits(b.x), bf16bits(b.y), bf16bits(b.z), bf16bits(b.w) };
    *(uint4*)(out + i) = *(const uint4*)s;
}

// three weights in one launch (per-block pointer select)
__global__ __launch_bounds__(256)
void f2b3_kernel(const float* __restrict__ i0, const float* __restrict__ i1,
                 const float* __restrict__ i2, __hip_bfloat16* __restrict__ o0,
                 __hip_bfloat16* __restrict__ o1, __hip_bfloat16* __restrict__ o2,
                 int per)
{
    const int sel = blockIdx.x / per, rem = blockIdx.x % per;
    const float* in = sel == 0 ? i0 : (sel == 1 ? i1 : i2);
    __hip_bfloat16* out = sel == 0 ? o0 : (sel == 1 ? o1 : o2);
    const size_t i = ((size_t)rem * 256 + threadIdx.x) * 8;
    float4 a = *(const float4*)(in + i);
    float4 b = *(const float4*)(in + i + 4);
    short s[8] = { bf16bits(a.x), bf16bits(a.y), bf16bits(a.z), bf16bits(a.w),
                   bf16bits(b.x), bf16bits(b.y), bf16bits(b.z), bf16bits(b.w) };
    *(uint4*)(out + i) = *(const uint4*)s;
}

// ---------------------------------------------------------------------------
// m97-structure MFMA GEMM bits shared by gemm_qkv / gemm_mfma.
// ---------------------------------------------------------------------------
#define BKg 32

__device__ inline void async16(const __hip_bfloat16* g, short* l) {
    __builtin_amdgcn_global_load_lds(
        (const __attribute__((address_space(1))) void*)g,
        (__attribute__((address_space(3))) void*)l, 16, 0, 0);
}

// ---------------------------------------------------------------------------
// Merged QKV GEMM: one dispatch, 1536 blocks (3x 512) -> ~6 blocks/CU capacity
// nsel = blockIdx.x>>4 selects weight + output: 0->q, 1->k, 2->vt(transposed).
// ---------------------------------------------------------------------------
__global__ __launch_bounds__(256)
void gemm_qkv(const __hip_bfloat16* __restrict__ A,
              const __hip_bfloat16* __restrict__ wq,
              const __hip_bfloat16* __restrict__ wk,
              const __hip_bfloat16* __restrict__ wv,
              __hip_bfloat16* __restrict__ q,
              __hip_bfloat16* __restrict__ k,
              __hip_bfloat16* __restrict__ vt)
{
    __shared__ __align__(16) short sA[128 * BKg];
    __shared__ __align__(16) short sB[128 * BKg];

    const int tid  = threadIdx.x;
    const int w    = tid >> 6;
    const int lane = tid & 63;
    const int l15  = lane & 15;
    const int quad = lane >> 4;

    const int nsel = (int)blockIdx.x >> 4;          // 0:q 1:k 2:v
    const int n0   = ((int)blockIdx.x & 15) * 128;  // within [0, 2048)
    const int m0   = (int)blockIdx.y * 128;
    const __hip_bfloat16* W = nsel == 0 ? wq : (nsel == 1 ? wk : wv);

    const int sr0  = w * 32 + (lane >> 2);
    const int scol = (lane & 3) * 8;
    const int wm = (w >> 1) * 64;
    const int wn = (w & 1) * 64;

    f32x4 acc[4][4];
    #pragma unroll
    for (int i = 0; i < 4; i++)
        #pragma unroll
        for (int j = 0; j < 4; j++) acc[i][j] = (f32x4)(0.0f);

    for (int k0 = 0; k0 < D_; k0 += BKg) {
        #pragma unroll
        for (int t = 0; t < 2; t++) {
            const int r = sr0 + t * 16;
            async16(A + (size_t)(m0 + r) * D_ + k0 + scol, sA + (w * 2 + t) * 512);
            async16(W + (size_t)(n0 + r) * D_ + k0 + scol, sB + (w * 2 + t) * 512);
        }
        __syncthreads();

        bf16x8 af[4], bf[4];
        #pragma unroll
        for (int i = 0; i < 4; i++)
            af[i] = *(const bf16x8*)(sA + (wm + i * 16 + l15) * BKg + quad * 8);
        #pragma unroll
        for (int j = 0; j < 4; j++)
            bf[j] = *(const bf16x8*)(sB + (wn + j * 16 + l15) * BKg + quad * 8);
        #pragma unroll
        for (int i = 0; i < 4; i++)
            #pragma unroll
            for (int j = 0; j < 4; j++)
                acc[i][j] = __builtin_amdgcn_mfma_f32_16x16x32_bf16(af[i], bf[j], acc[i][j], 0, 0, 0);
        __syncthreads();
    }

    __hip_bfloat16* out = nsel == 0 ? q : (nsel == 1 ? k : vt);
    #pragma unroll
    for (int i = 0; i < 4; i++) {
        #pragma unroll
        for (int r = 0; r < 4; r++) {
            const int m = m0 + wm + i * 16 + quad * 4 + r;
            const int b = m / S_, s = m % S_;
            #pragma unroll
            for (int j = 0; j < 4; j++) {
                const int n  = n0 + wn + j * 16 + l15;
                const int h  = n / DH_, dh = n % DH_;
                const size_t idx = (nsel == 2)
                    ? (((size_t)(b * H_ + h)) * DH_ + dh) * S_ + s
                    : (((size_t)(b * H_ + h)) * S_ + s) * DH_ + dh;
                out[idx] = __float2bfloat16(acc[i][j][r]);
            }
        }
    }
}

// ---------------------------------------------------------------------------
// Final projection GEMM: C[M,N] = A[M,K] * W[N,K]^T, bf16 in, fp32 out.
// ---------------------------------------------------------------------------
__global__ __launch_bounds__(256)
void gemm_mfma(const __hip_bfloat16* __restrict__ A,
               const __hip_bfloat16* __restrict__ W,
               float* __restrict__ out, int M, int N, int K)
{
    __shared__ __align__(16) short sA[128 * BKg];
    __shared__ __align__(16) short sB[128 * BKg];

    const int tid  = threadIdx.x;
    const int w    = tid >> 6;
    const int lane = tid & 63;
    const int l15  = lane & 15;
    const int quad = lane >> 4;

    const int m0 = blockIdx.y * 128;
    const int n0 = blockIdx.x * 128;

    const int sr0 = w * 32 + (lane >> 2);
    const int scol = (lane & 3) * 8;
    const int wm = (w >> 1) * 64;
    const int wn = (w & 1) * 64;

    f32x4 acc[4][4];
    #pragma unroll
    for (int i = 0; i < 4; i++)
        #pragma unroll
        for (int j = 0; j < 4; j++) acc[i][j] = (f32x4)(0.0f);

    for (int k0 = 0; k0 < K; k0 += BKg) {
        #pragma unroll
        for (int t = 0; t < 2; t++) {
            const int r = sr0 + t * 16;
            async16(A + (size_t)(m0 + r) * K + k0 + scol, sA + (w * 2 + t) * 512);
            async16(W + (size_t)(n0 + r) * K + k0 + scol, sB + (w * 2 + t) * 512);
        }
        __syncthreads();

        bf16x8 af[4], bf[4];
        #pragma unroll
        for (int i = 0; i < 4; i++)
            af[i] = *(const bf16x8*)(sA + (wm + i * 16 + l15) * BKg + quad * 8);
        #pragma unroll
        for (int j = 0; j < 4; j++)
            bf[j] = *(const bf16x8*)(sB + (wn + j * 16 + l15) * BKg + quad * 8);
        #pragma unroll
        for (int i = 0; i < 4; i++)
            #pragma unroll
            for (int j = 0; j < 4; j++)
                acc[i][j] = __builtin_amdgcn_mfma_f32_16x16x32_bf16(af[i], bf[j], acc[i][j], 0, 0, 0);
        __syncthreads();
    }

    #pragma unroll
    for (int i = 0; i < 4; i++) {
        #pragma unroll
        for (int r = 0; r < 4; r++) {
            const int m = m0 + wm + i * 16 + quad * 4 + r;
            #pragma unroll
            for (int j = 0; j < 4; j++) {
                const int n = n0 + wn + j * 16 + l15;
                out[(size_t)m * N + n] = acc[i][j][r];
            }
        }
    }
}

// ---------------------------------------------------------------------------
// RoPE on q AND k in one launch; cos/sin fp32 [S, DH].
// ---------------------------------------------------------------------------
__global__ __launch_bounds__(256)
void rope2_kernel(__hip_bfloat16* __restrict__ q, __hip_bfloat16* __restrict__ k,
                  const float* __restrict__ cos_, const float* __restrict__ sin_,
                  int per)
{
    const int sel = blockIdx.x / per, rem = blockIdx.x % per;
    __hip_bfloat16* base = sel == 0 ? q : k;
    const size_t i = (size_t)rem * blockDim.x + threadIdx.x;
    const int dh = (int)(i & 63);
    const size_t row = i >> 6;
    const int s = (int)(row % S_);
    __hip_bfloat16* p = base + row * DH_;

    const float x1 = __bfloat162float(p[dh]);
    const float x2 = __bfloat162float(p[dh + 64]);
    const float c1 = cos_[s * DH_ + dh];
    const float s1 = sin_[s * DH_ + dh];
    const float c2 = cos_[s * DH_ + dh + 64];
    const float s2 = sin_[s * DH_ + dh + 64];

    p[dh]      = __float2bfloat16(x1 * c1 - x2 * s1);
    p[dh + 64] = __float2bfloat16(x2 * c2 + x1 * s2);
}

// ---------------------------------------------------------------------------
// Flash attention v3.1: 64-row q-tiles (4 waves x 16 rows), kv-tile 64,
// register-prefetch double buffering, deferred l-reduction.
//
// v3 lesson (rocprof): amdgpu_waves_per_eu(3) pins only the MIN; LLVM
// targeted 6 waves/EU (80 VGPR) and spilled the 32-reg kreg/vreg prefetch
// every iteration -> 491 MB HBM writes (measured), cancelling the
// occupancy win. Pin (3,3): budget 512/3=170 regs, kernel needs ~130,
// no spill, still 3 blocks/CU (LDS 44 KB).
// ---------------------------------------------------------------------------
#define KSTR 136
#define VSTR 72
#define PSTR 72

__global__ __launch_bounds__(256) __attribute__((amdgpu_waves_per_eu(3, 3)))
void attn_mfma(const __hip_bfloat16* __restrict__ q,
               const __hip_bfloat16* __restrict__ k,
               const __hip_bfloat16* __restrict__ vt,
               __hip_bfloat16* __restrict__ vals)
{
    __shared__ __align__(16) short sK[64 * KSTR];
    __shared__ __align__(16) short sV[128 * VSTR];
    __shared__ __align__(16) short sP[4 * 16 * PSTR];

    // 1D grid, longest-first: rank 0 -> qtile 31 (32 kv iters)
    const int idx   = (int)blockIdx.x;
    const int bh    = idx & 31;           // B_*H_ = 32
    const int qtile = 31 - (idx >> 5);    // 32 qtiles of 64 rows
    const int q0    = qtile * 64;
    const int tid   = threadIdx.x;
    const int w     = tid >> 6;
    const int lane  = tid & 63;
    const int l15   = lane & 15;
    const int quad  = lane >> 4;
    const int qb    = q0 + w * 16;        // this wave's 16 q-rows

    bf16x8 qf[4];
    {
        const __hip_bfloat16* qrow =
            q + ((size_t)bh * S_ + qb + l15) * DH_ + quad * 8;
        #pragma unroll
        for (int c = 0; c < 4; c++)
            qf[c] = *(const bf16x8*)(qrow + c * 32);
    }

    f32x4 o[8];
    #pragma unroll
    for (int d = 0; d < 8; d++) o[d] = (f32x4)(0.0f);
    float mrow[4], lrow[4];
    #pragma unroll
    for (int r = 0; r < 4; r++) { mrow[r] = -1e30f; lrow[r] = 0.f; }

    const float scale = 0.08838834764831845f;

    const int kr = tid >> 2, kc = (tid & 3) * 32;
    const int vr = tid >> 1, vc = (tid & 1) * 32;
    const int niter = qtile + 1;

    uint4 kreg[4], vreg[4];
    {
        const __hip_bfloat16* kg = k + ((size_t)bh * S_ + kr) * DH_ + kc;
        const __hip_bfloat16* vg = vt + ((size_t)bh * DH_ + vr) * S_ + vc;
        #pragma unroll
        for (int u = 0; u < 4; u++) kreg[u] = *(const uint4*)(kg + u * 8);
        #pragma unroll
        for (int u = 0; u < 4; u++) vreg[u] = *(const uint4*)(vg + u * 8);
    }

    for (int it = 0; it < niter; ++it) {
        const int kv0 = it * 64;

        {
            short* dk = &sK[kr * KSTR + kc];
            #pragma unroll
            for (int u = 0; u < 4; u++) *(uint4*)(dk + u * 8) = kreg[u];
            short* dv = &sV[vr * VSTR + vc];
            #pragma unroll
            for (int u = 0; u < 4; u++) *(uint4*)(dv + u * 8) = vreg[u];
        }
        __syncthreads();

        if (it + 1 < niter) {
            const int nv = kv0 + 64;
            const __hip_bfloat16* kg = k + ((size_t)bh * S_ + nv + kr) * DH_ + kc;
            const __hip_bfloat16* vg = vt + ((size_t)bh * DH_ + vr) * S_ + nv + vc;
            #pragma unroll
            for (int u = 0; u < 4; u++) kreg[u] = *(const uint4*)(kg + u * 8);
            #pragma unroll
            for (int u = 0; u < 4; u++) vreg[u] = *(const uint4*)(vg + u * 8);
        }

        // QK^T for this wave's 16 rows x 64 kv
        f32x4 s[4];
        #pragma unroll
        for (int n = 0; n < 4; n++) s[n] = (f32x4)(0.0f);
        #pragma unroll
        for (int n = 0; n < 4; n++) {
            const short* kp = &sK[(n * 16 + l15) * KSTR + quad * 8];
            #pragma unroll
            for (int c = 0; c < 4; c++) {
                bf16x8 kf = *(const bf16x8*)(kp + c * 32);
                s[n] = __builtin_amdgcn_mfma_f32_16x16x32_bf16(qf[c], kf, s[n], 0, 0, 0);
            }
        }

        // softmax (online, deferred l-reduce)
        {
            const bool msk = (kv0 + 63 > qb);
            float sv[4][4];
            #pragma unroll
            for (int n = 0; n < 4; n++)
                #pragma unroll
                for (int r = 0; r < 4; r++) {
                    float x = s[n][r] * scale;
                    if (msk) {
                        const int kvg = kv0 + n * 16 + l15;
                        const int qg  = qb + quad * 4 + r;
                        if (kvg > qg) x = -1e30f;
                    }
                    sv[n][r] = x;
                }

            float alpha[4];
            #pragma unroll
            for (int r = 0; r < 4; r++) {
                float v = fmaxf(fmaxf(sv[0][r], sv[1][r]), fmaxf(sv[2][r], sv[3][r]));
                #pragma unroll
                for (int m2 = 8; m2; m2 >>= 1)
                    v = fmaxf(v, __shfl_xor(v, m2, 64));
                const float mn = fmaxf(mrow[r], v);
                alpha[r] = __expf(mrow[r] - mn);
                mrow[r] = mn;
            }
            #pragma unroll
            for (int r = 0; r < 4; r++) {
                float rs = 0.f;
                #pragma unroll
                for (int n = 0; n < 4; n++) {
                    const float p = __expf(sv[n][r] - mrow[r]);
                    sv[n][r] = p;
                    rs += p;
                }
                lrow[r] = lrow[r] * alpha[r] + rs;
            }
            #pragma unroll
            for (int d = 0; d < 8; d++)
                #pragma unroll
                for (int r = 0; r < 4; r++)
                    o[d][r] *= alpha[r];

            short* pb = &sP[(w * 16) * PSTR];
            #pragma unroll
            for (int n = 0; n < 4; n++)
                #pragma unroll
                for (int r = 0; r < 4; r++)
                    pb[(quad * 4 + r) * PSTR + n * 16 + l15] = bf16bits(sv[n][r]);
        }

        // PV
        #pragma unroll
        for (int c = 0; c < 2; c++) {
            bf16x8 pf = *(const bf16x8*)(&sP[(w * 16 + l15) * PSTR + c * 32 + quad * 8]);
            #pragma unroll
            for (int d = 0; d < 8; d++) {
                bf16x8 vf = *(const bf16x8*)(&sV[(d * 16 + l15) * VSTR + c * 32 + quad * 8]);
                o[d] = __builtin_amdgcn_mfma_f32_16x16x32_bf16(pf, vf, o[d], 0, 0, 0);
            }
        }
        __syncthreads();
    }

    const int b = bh >> 4, h = bh & 15;
    #pragma unroll
    for (int r = 0; r < 4; r++) {
        float l = lrow[r];
        #pragma unroll
        for (int m2 = 8; m2; m2 >>= 1)
            l += __shfl_xor(l, m2, 64);
        const float inv = 1.0f / l;
        const int qg = qb + quad * 4 + r;
        #pragma unroll
        for (int d = 0; d < 8; d++) {
            const int col = d * 16 + l15;
            vals[(((size_t)b * S_ + qg) * H_ + h) * DH_ + col] =
                __float2bfloat16(o[d][r] * inv);
        }
    }
}

// ---------------------------------------------------------------------------
extern "C" void kernel_launch(void* const* d_in, const int* in_sizes, int n_in,
                              void* d_out, int out_size, void* d_ws, size_t ws_size,
                              hipStream_t stream)
{
    const float* x    = (const float*)d_in[0];
    const float* cos_ = (const float*)d_in[1];
    const float* sin_ = (const float*)d_in[2];
    const float* Wq   = (const float*)d_in[3];
    const float* Wk   = (const float*)d_in[4];
    const float* Wv   = (const float*)d_in[5];
    const float* Wo   = (const float*)d_in[6];
    float* out = (float*)d_out;

    const size_t NELEM = (size_t)B_ * S_ * D_;       // 8388608
    const size_t WELEM = (size_t)D_ * D_;            // 4194304

    // d_out scratch during QKV phase: 3 bf16 weights (25.2 MB <= 33.5 MB)
    __hip_bfloat16* wqb = (__hip_bfloat16*)d_out;
    __hip_bfloat16* wkb = wqb + WELEM;
    __hip_bfloat16* wvb = wkb + WELEM;
    // ws (67 MB): q,k,vt,vals. xb shares the vals region (dead before attn
    // writes vals); Wo-bf16 reuses q region (dead after attn).
    __hip_bfloat16* q    = (__hip_bfloat16*)d_ws;
    __hip_bfloat16* k    = q + NELEM;
    __hip_bfloat16* vt   = k + NELEM;
    __hip_bfloat16* vals = vt + NELEM;
    __hip_bfloat16* xb   = vals;
    __hip_bfloat16* wob  = q;

    const int M = B_ * S_, N = D_, K = D_;
    const int xcb = (int)(NELEM / (256 * 8));        // 4096 blocks
    const int wcb = (int)(WELEM / (256 * 8));        // 2048 blocks

    f2b_kernel<<<xcb, 256, 0, stream>>>(x, xb);
    f2b3_kernel<<<3 * wcb, 256, 0, stream>>>(Wq, Wk, Wv, wqb, wkb, wvb, wcb);

    gemm_qkv<<<dim3(3 * N / 128, M / 128), 256, 0, stream>>>(xb, wqb, wkb, wvb, q, k, vt);

    const int rope_blocks = B_ * H_ * S_ * 64 / 256;  // per tensor
    rope2_kernel<<<2 * rope_blocks, 256, 0, stream>>>(q, k, cos_, sin_, rope_blocks);

    // 32 qtiles x 32 bh, longest-first for LPT backfill
    attn_mfma<<<dim3(32 * (B_ * H_)), 256, 0, stream>>>(q, k, vt, vals);

    f2b_kernel<<<wcb, 256, 0, stream>>>(Wo, wob);
    gemm_mfma<<<dim3(N / 128, M / 128), 256, 0, stream>>>(vals, wob, out, M, N, K);
}

// Round 3
// 544.160 us; speedup vs baseline: 1.0049x; 1.0049x over previous
//
#include <hip/hip_runtime.h>
#include <hip/hip_bf16.h>

#define B_  2
#define S_  2048
#define D_  2048
#define H_  16
#define DH_ 128

typedef __attribute__((ext_vector_type(8))) short bf16x8;
typedef __attribute__((ext_vector_type(4))) float f32x4;

__device__ inline short bf16bits(float v) {
    __hip_bfloat16 h = __float2bfloat16(v);
    return *reinterpret_cast<short*>(&h);
}

// ---------------------------------------------------------------------------
// fp32 -> bf16 cast, 8 elements/thread.
// ---------------------------------------------------------------------------
__global__ __launch_bounds__(256)
void f2b_kernel(const float* __restrict__ in, __hip_bfloat16* __restrict__ out)
{
    const size_t i = ((size_t)blockIdx.x * 256 + threadIdx.x) * 8;
    float4 a = *(const float4*)(in + i);
    float4 b = *(const float4*)(in + i + 4);
    short s[8] = { bf16bits(a.x), bf16bits(a.y), bf16bits(a.z), bf16bits(a.w),
                   bf16bits(b.x), bf16bits(b.y), bf16bits(b.z), bf16bits(b.w) };
    *(uint4*)(out + i) = *(const uint4*)s;
}

// three weights in one launch (per-block pointer select)
__global__ __launch_bounds__(256)
void f2b3_kernel(const float* __restrict__ i0, const float* __restrict__ i1,
                 const float* __restrict__ i2, __hip_bfloat16* __restrict__ o0,
                 __hip_bfloat16* __restrict__ o1, __hip_bfloat16* __restrict__ o2,
                 int per)
{
    const int sel = blockIdx.x / per, rem = blockIdx.x % per;
    const float* in = sel == 0 ? i0 : (sel == 1 ? i1 : i2);
    __hip_bfloat16* out = sel == 0 ? o0 : (sel == 1 ? o1 : o2);
    const size_t i = ((size_t)rem * 256 + threadIdx.x) * 8;
    float4 a = *(const float4*)(in + i);
    float4 b = *(const float4*)(in + i + 4);
    short s[8] = { bf16bits(a.x), bf16bits(a.y), bf16bits(a.z), bf16bits(a.w),
                   bf16bits(b.x), bf16bits(b.y), bf16bits(b.z), bf16bits(b.w) };
    *(uint4*)(out + i) = *(const uint4*)s;
}

// ---------------------------------------------------------------------------
// m97-structure MFMA GEMM bits shared by gemm_qkv / gemm_mfma.
// ---------------------------------------------------------------------------
#define BKg 32

__device__ inline void async16(const __hip_bfloat16* g, short* l) {
    __builtin_amdgcn_global_load_lds(
        (const __attribute__((address_space(1))) void*)g,
        (__attribute__((address_space(3))) void*)l, 16, 0, 0);
}

// ---------------------------------------------------------------------------
// Merged QKV GEMM: one dispatch, 1536 blocks (3x 512) -> ~6 blocks/CU capacity
// nsel = blockIdx.x>>4 selects weight + output: 0->q, 1->k, 2->vt(transposed).
// ---------------------------------------------------------------------------
__global__ __launch_bounds__(256)
void gemm_qkv(const __hip_bfloat16* __restrict__ A,
              const __hip_bfloat16* __restrict__ wq,
              const __hip_bfloat16* __restrict__ wk,
              const __hip_bfloat16* __restrict__ wv,
              __hip_bfloat16* __restrict__ q,
              __hip_bfloat16* __restrict__ k,
              __hip_bfloat16* __restrict__ vt)
{
    __shared__ __align__(16) short sA[128 * BKg];
    __shared__ __align__(16) short sB[128 * BKg];

    const int tid  = threadIdx.x;
    const int w    = tid >> 6;
    const int lane = tid & 63;
    const int l15  = lane & 15;
    const int quad = lane >> 4;

    const int nsel = (int)blockIdx.x >> 4;          // 0:q 1:k 2:v
    const int n0   = ((int)blockIdx.x & 15) * 128;  // within [0, 2048)
    const int m0   = (int)blockIdx.y * 128;
    const __hip_bfloat16* W = nsel == 0 ? wq : (nsel == 1 ? wk : wv);

    const int sr0  = w * 32 + (lane >> 2);
    const int scol = (lane & 3) * 8;
    const int wm = (w >> 1) * 64;
    const int wn = (w & 1) * 64;

    f32x4 acc[4][4];
    #pragma unroll
    for (int i = 0; i < 4; i++)
        #pragma unroll
        for (int j = 0; j < 4; j++) acc[i][j] = (f32x4)(0.0f);

    for (int k0 = 0; k0 < D_; k0 += BKg) {
        #pragma unroll
        for (int t = 0; t < 2; t++) {
            const int r = sr0 + t * 16;
            async16(A + (size_t)(m0 + r) * D_ + k0 + scol, sA + (w * 2 + t) * 512);
            async16(W + (size_t)(n0 + r) * D_ + k0 + scol, sB + (w * 2 + t) * 512);
        }
        __syncthreads();

        bf16x8 af[4], bf[4];
        #pragma unroll
        for (int i = 0; i < 4; i++)
            af[i] = *(const bf16x8*)(sA + (wm + i * 16 + l15) * BKg + quad * 8);
        #pragma unroll
        for (int j = 0; j < 4; j++)
            bf[j] = *(const bf16x8*)(sB + (wn + j * 16 + l15) * BKg + quad * 8);
        #pragma unroll
        for (int i = 0; i < 4; i++)
            #pragma unroll
            for (int j = 0; j < 4; j++)
                acc[i][j] = __builtin_amdgcn_mfma_f32_16x16x32_bf16(af[i], bf[j], acc[i][j], 0, 0, 0);
        __syncthreads();
    }

    __hip_bfloat16* out = nsel == 0 ? q : (nsel == 1 ? k : vt);
    #pragma unroll
    for (int i = 0; i < 4; i++) {
        #pragma unroll
        for (int r = 0; r < 4; r++) {
            const int m = m0 + wm + i * 16 + quad * 4 + r;
            const int b = m / S_, s = m % S_;
            #pragma unroll
            for (int j = 0; j < 4; j++) {
                const int n  = n0 + wn + j * 16 + l15;
                const int h  = n / DH_, dh = n % DH_;
                const size_t idx = (nsel == 2)
                    ? (((size_t)(b * H_ + h)) * DH_ + dh) * S_ + s
                    : (((size_t)(b * H_ + h)) * S_ + s) * DH_ + dh;
                out[idx] = __float2bfloat16(acc[i][j][r]);
            }
        }
    }
}

// ---------------------------------------------------------------------------
// Final projection GEMM: C[M,N] = A[M,K] * W[N,K]^T, bf16 in, fp32 out.
// ---------------------------------------------------------------------------
__global__ __launch_bounds__(256)
void gemm_mfma(const __hip_bfloat16* __restrict__ A,
               const __hip_bfloat16* __restrict__ W,
               float* __restrict__ out, int M, int N, int K)
{
    __shared__ __align__(16) short sA[128 * BKg];
    __shared__ __align__(16) short sB[128 * BKg];

    const int tid  = threadIdx.x;
    const int w    = tid >> 6;
    const int lane = tid & 63;
    const int l15  = lane & 15;
    const int quad = lane >> 4;

    const int m0 = blockIdx.y * 128;
    const int n0 = blockIdx.x * 128;

    const int sr0 = w * 32 + (lane >> 2);
    const int scol = (lane & 3) * 8;
    const int wm = (w >> 1) * 64;
    const int wn = (w & 1) * 64;

    f32x4 acc[4][4];
    #pragma unroll
    for (int i = 0; i < 4; i++)
        #pragma unroll
        for (int j = 0; j < 4; j++) acc[i][j] = (f32x4)(0.0f);

    for (int k0 = 0; k0 < K; k0 += BKg) {
        #pragma unroll
        for (int t = 0; t < 2; t++) {
            const int r = sr0 + t * 16;
            async16(A + (size_t)(m0 + r) * K + k0 + scol, sA + (w * 2 + t) * 512);
            async16(W + (size_t)(n0 + r) * K + k0 + scol, sB + (w * 2 + t) * 512);
        }
        __syncthreads();

        bf16x8 af[4], bf[4];
        #pragma unroll
        for (int i = 0; i < 4; i++)
            af[i] = *(const bf16x8*)(sA + (wm + i * 16 + l15) * BKg + quad * 8);
        #pragma unroll
        for (int j = 0; j < 4; j++)
            bf[j] = *(const bf16x8*)(sB + (wn + j * 16 + l15) * BKg + quad * 8);
        #pragma unroll
        for (int i = 0; i < 4; i++)
            #pragma unroll
            for (int j = 0; j < 4; j++)
                acc[i][j] = __builtin_amdgcn_mfma_f32_16x16x32_bf16(af[i], bf[j], acc[i][j], 0, 0, 0);
        __syncthreads();
    }

    #pragma unroll
    for (int i = 0; i < 4; i++) {
        #pragma unroll
        for (int r = 0; r < 4; r++) {
            const int m = m0 + wm + i * 16 + quad * 4 + r;
            #pragma unroll
            for (int j = 0; j < 4; j++) {
                const int n = n0 + wn + j * 16 + l15;
                out[(size_t)m * N + n] = acc[i][j][r];
            }
        }
    }
}

// ---------------------------------------------------------------------------
// RoPE on q AND k in one launch; cos/sin fp32 [S, DH].
// ---------------------------------------------------------------------------
__global__ __launch_bounds__(256)
void rope2_kernel(__hip_bfloat16* __restrict__ q, __hip_bfloat16* __restrict__ k,
                  const float* __restrict__ cos_, const float* __restrict__ sin_,
                  int per)
{
    const int sel = blockIdx.x / per, rem = blockIdx.x % per;
    __hip_bfloat16* base = sel == 0 ? q : k;
    const size_t i = (size_t)rem * blockDim.x + threadIdx.x;
    const int dh = (int)(i & 63);
    const size_t row = i >> 6;
    const int s = (int)(row % S_);
    __hip_bfloat16* p = base + row * DH_;

    const float x1 = __bfloat162float(p[dh]);
    const float x2 = __bfloat162float(p[dh + 64]);
    const float c1 = cos_[s * DH_ + dh];
    const float s1 = sin_[s * DH_ + dh];
    const float c2 = cos_[s * DH_ + dh + 64];
    const float s2 = sin_[s * DH_ + dh + 64];

    p[dh]      = __float2bfloat16(x1 * c1 - x2 * s1);
    p[dh + 64] = __float2bfloat16(x2 * c2 + x1 * s2);
}

// ---------------------------------------------------------------------------
// Flash attention v3.2: 64-row q-tiles (4 waves x 16 rows), kv-tile 64,
// register-prefetch double buffering, deferred l-reduction.
//
// Register-spill history (rocprof evidence):
//  v3   amdgpu_waves_per_eu(3):   VGPR 80, WRITE_SIZE 491 MB (kreg/vreg
//       spilled every iter; spill math: 48 regs x 67.5K wave-iters x 256 B
//       = ~500 MB. Matches.)
//  v3.1 amdgpu_waves_per_eu(3,3): bit-identical codegen -> the GNU-style
//       attribute never reaches the backend in this toolchain.
//  v3.2 __launch_bounds__(256, 2): the documented clang path for min
//       waves/EU. Declares 2 waves/EU -> 256-VGPR budget; live state ~140
//       allocates spill-free; runtime occupancy still 3 waves/EU
//       (floor(512/~140) = 3, LDS 44 KB = 3 blocks/CU).
// ---------------------------------------------------------------------------
#define KSTR 136
#define VSTR 72
#define PSTR 72

__global__ __launch_bounds__(256, 2)
void attn_mfma(const __hip_bfloat16* __restrict__ q,
               const __hip_bfloat16* __restrict__ k,
               const __hip_bfloat16* __restrict__ vt,
               __hip_bfloat16* __restrict__ vals)
{
    __shared__ __align__(16) short sK[64 * KSTR];
    __shared__ __align__(16) short sV[128 * VSTR];
    __shared__ __align__(16) short sP[4 * 16 * PSTR];

    // 1D grid, longest-first: rank 0 -> qtile 31 (32 kv iters)
    const int idx   = (int)blockIdx.x;
    const int bh    = idx & 31;           // B_*H_ = 32
    const int qtile = 31 - (idx >> 5);    // 32 qtiles of 64 rows
    const int q0    = qtile * 64;
    const int tid   = threadIdx.x;
    const int w     = tid >> 6;
    const int lane  = tid & 63;
    const int l15   = lane & 15;
    const int quad  = lane >> 4;
    const int qb    = q0 + w * 16;        // this wave's 16 q-rows

    bf16x8 qf[4];
    {
        const __hip_bfloat16* qrow =
            q + ((size_t)bh * S_ + qb + l15) * DH_ + quad * 8;
        #pragma unroll
        for (int c = 0; c < 4; c++)
            qf[c] = *(const bf16x8*)(qrow + c * 32);
    }

    f32x4 o[8];
    #pragma unroll
    for (int d = 0; d < 8; d++) o[d] = (f32x4)(0.0f);
    float mrow[4], lrow[4];
    #pragma unroll
    for (int r = 0; r < 4; r++) { mrow[r] = -1e30f; lrow[r] = 0.f; }

    const float scale = 0.08838834764831845f;

    const int kr = tid >> 2, kc = (tid & 3) * 32;
    const int vr = tid >> 1, vc = (tid & 1) * 32;
    const int niter = qtile + 1;

    uint4 kreg[4], vreg[4];
    {
        const __hip_bfloat16* kg = k + ((size_t)bh * S_ + kr) * DH_ + kc;
        const __hip_bfloat16* vg = vt + ((size_t)bh * DH_ + vr) * S_ + vc;
        #pragma unroll
        for (int u = 0; u < 4; u++) kreg[u] = *(const uint4*)(kg + u * 8);
        #pragma unroll
        for (int u = 0; u < 4; u++) vreg[u] = *(const uint4*)(vg + u * 8);
    }

    for (int it = 0; it < niter; ++it) {
        const int kv0 = it * 64;

        {
            short* dk = &sK[kr * KSTR + kc];
            #pragma unroll
            for (int u = 0; u < 4; u++) *(uint4*)(dk + u * 8) = kreg[u];
            short* dv = &sV[vr * VSTR + vc];
            #pragma unroll
            for (int u = 0; u < 4; u++) *(uint4*)(dv + u * 8) = vreg[u];
        }
        __syncthreads();

        if (it + 1 < niter) {
            const int nv = kv0 + 64;
            const __hip_bfloat16* kg = k + ((size_t)bh * S_ + nv + kr) * DH_ + kc;
            const __hip_bfloat16* vg = vt + ((size_t)bh * DH_ + vr) * S_ + nv + vc;
            #pragma unroll
            for (int u = 0; u < 4; u++) kreg[u] = *(const uint4*)(kg + u * 8);
            #pragma unroll
            for (int u = 0; u < 4; u++) vreg[u] = *(const uint4*)(vg + u * 8);
        }

        // QK^T for this wave's 16 rows x 64 kv
        f32x4 s[4];
        #pragma unroll
        for (int n = 0; n < 4; n++) s[n] = (f32x4)(0.0f);
        #pragma unroll
        for (int n = 0; n < 4; n++) {
            const short* kp = &sK[(n * 16 + l15) * KSTR + quad * 8];
            #pragma unroll
            for (int c = 0; c < 4; c++) {
                bf16x8 kf = *(const bf16x8*)(kp + c * 32);
                s[n] = __builtin_amdgcn_mfma_f32_16x16x32_bf16(qf[c], kf, s[n], 0, 0, 0);
            }
        }

        // softmax (online, deferred l-reduce)
        {
            const bool msk = (kv0 + 63 > qb);
            float sv[4][4];
            #pragma unroll
            for (int n = 0; n < 4; n++)
                #pragma unroll
                for (int r = 0; r < 4; r++) {
                    float x = s[n][r] * scale;
                    if (msk) {
                        const int kvg = kv0 + n * 16 + l15;
                        const int qg  = qb + quad * 4 + r;
                        if (kvg > qg) x = -1e30f;
                    }
                    sv[n][r] = x;
                }

            float alpha[4];
            #pragma unroll
            for (int r = 0; r < 4; r++) {
                float v = fmaxf(fmaxf(sv[0][r], sv[1][r]), fmaxf(sv[2][r], sv[3][r]));
                #pragma unroll
                for (int m2 = 8; m2; m2 >>= 1)
                    v = fmaxf(v, __shfl_xor(v, m2, 64));
                const float mn = fmaxf(mrow[r], v);
                alpha[r] = __expf(mrow[r] - mn);
                mrow[r] = mn;
            }
            #pragma unroll
            for (int r = 0; r < 4; r++) {
                float rs = 0.f;
                #pragma unroll
                for (int n = 0; n < 4; n++) {
                    const float p = __expf(sv[n][r] - mrow[r]);
                    sv[n][r] = p;
                    rs += p;
                }
                lrow[r] = lrow[r] * alpha[r] + rs;
            }
            #pragma unroll
            for (int d = 0; d < 8; d++)
                #pragma unroll
                for (int r = 0; r < 4; r++)
                    o[d][r] *= alpha[r];

            short* pb = &sP[(w * 16) * PSTR];
            #pragma unroll
            for (int n = 0; n < 4; n++)
                #pragma unroll
                for (int r = 0; r < 4; r++)
                    pb[(quad * 4 + r) * PSTR + n * 16 + l15] = bf16bits(sv[n][r]);
        }

        // PV
        #pragma unroll
        for (int c = 0; c < 2; c++) {
            bf16x8 pf = *(const bf16x8*)(&sP[(w * 16 + l15) * PSTR + c * 32 + quad * 8]);
            #pragma unroll
            for (int d = 0; d < 8; d++) {
                bf16x8 vf = *(const bf16x8*)(&sV[(d * 16 + l15) * VSTR + c * 32 + quad * 8]);
                o[d] = __builtin_amdgcn_mfma_f32_16x16x32_bf16(pf, vf, o[d], 0, 0, 0);
            }
        }
        __syncthreads();
    }

    const int b = bh >> 4, h = bh & 15;
    #pragma unroll
    for (int r = 0; r < 4; r++) {
        float l = lrow[r];
        #pragma unroll
        for (int m2 = 8; m2; m2 >>= 1)
            l += __shfl_xor(l, m2, 64);
        const float inv = 1.0f / l;
        const int qg = qb + quad * 4 + r;
        #pragma unroll
        for (int d = 0; d < 8; d++) {
            const int col = d * 16 + l15;
            vals[(((size_t)b * S_ + qg) * H_ + h) * DH_ + col] =
                __float2bfloat16(o[d][r] * inv);
        }
    }
}

// ---------------------------------------------------------------------------
extern "C" void kernel_launch(void* const* d_in, const int* in_sizes, int n_in,
                              void* d_out, int out_size, void* d_ws, size_t ws_size,
                              hipStream_t stream)
{
    const float* x    = (const float*)d_in[0];
    const float* cos_ = (const float*)d_in[1];
    const float* sin_ = (const float*)d_in[2];
    const float* Wq   = (const float*)d_in[3];
    const float* Wk   = (const float*)d_in[4];
    const float* Wv   = (const float*)d_in[5];
    const float* Wo   = (const float*)d_in[6];
    float* out = (float*)d_out;

    const size_t NELEM = (size_t)B_ * S_ * D_;       // 8388608
    const size_t WELEM = (size_t)D_ * D_;            // 4194304

    // d_out scratch during QKV phase: 3 bf16 weights (25.2 MB <= 33.5 MB)
    __hip_bfloat16* wqb = (__hip_bfloat16*)d_out;
    __hip_bfloat16* wkb = wqb + WELEM;
    __hip_bfloat16* wvb = wkb + WELEM;
    // ws (67 MB): q,k,vt,vals. xb shares the vals region (dead before attn
    // writes vals); Wo-bf16 reuses q region (dead after attn).
    __hip_bfloat16* q    = (__hip_bfloat16*)d_ws;
    __hip_bfloat16* k    = q + NELEM;
    __hip_bfloat16* vt   = k + NELEM;
    __hip_bfloat16* vals = vt + NELEM;
    __hip_bfloat16* xb   = vals;
    __hip_bfloat16* wob  = q;

    const int M = B_ * S_, N = D_, K = D_;
    const int xcb = (int)(NELEM / (256 * 8));        // 4096 blocks
    const int wcb = (int)(WELEM / (256 * 8));        // 2048 blocks

    f2b_kernel<<<xcb, 256, 0, stream>>>(x, xb);
    f2b3_kernel<<<3 * wcb, 256, 0, stream>>>(Wq, Wk, Wv, wqb, wkb, wvb, wcb);

    gemm_qkv<<<dim3(3 * N / 128, M / 128), 256, 0, stream>>>(xb, wqb, wkb, wvb, q, k, vt);

    const int rope_blocks = B_ * H_ * S_ * 64 / 256;  // per tensor
    rope2_kernel<<<2 * rope_blocks, 256, 0, stream>>>(q, k, cos_, sin_, rope_blocks);

    // 32 qtiles x 32 bh, longest-first for LPT backfill
    attn_mfma<<<dim3(32 * (B_ * H_)), 256, 0, stream>>>(q, k, vt, vals);

    f2b_kernel<<<wcb, 256, 0, stream>>>(Wo, wob);
    gemm_mfma<<<dim3(N / 128, M / 128), 256, 0, stream>>>(vals, wob, out, M, N, K);
}

// Round 4
// 445.119 us; speedup vs baseline: 1.2285x; 1.2225x over previous
//
#include <hip/hip_runtime.h>
#include <hip/hip_bf16.h>

#define B_  2
#define S_  2048
#define D_  2048
#define H_  16
#define DH_ 128

typedef __attribute__((ext_vector_type(8))) short bf16x8;
typedef __attribute__((ext_vector_type(4))) float f32x4;

__device__ inline short bf16bits(float v) {
    __hip_bfloat16 h = __float2bfloat16(v);
    return *reinterpret_cast<short*>(&h);
}

// ---------------------------------------------------------------------------
// fp32 -> bf16 cast, 8 elements/thread.
// ---------------------------------------------------------------------------
__global__ __launch_bounds__(256)
void f2b_kernel(const float* __restrict__ in, __hip_bfloat16* __restrict__ out)
{
    const size_t i = ((size_t)blockIdx.x * 256 + threadIdx.x) * 8;
    float4 a = *(const float4*)(in + i);
    float4 b = *(const float4*)(in + i + 4);
    short s[8] = { bf16bits(a.x), bf16bits(a.y), bf16bits(a.z), bf16bits(a.w),
                   bf16bits(b.x), bf16bits(b.y), bf16bits(b.z), bf16bits(b.w) };
    *(uint4*)(out + i) = *(const uint4*)s;
}

// three weights in one launch (per-block pointer select)
__global__ __launch_bounds__(256)
void f2b3_kernel(const float* __restrict__ i0, const float* __restrict__ i1,
                 const float* __restrict__ i2, __hip_bfloat16* __restrict__ o0,
                 __hip_bfloat16* __restrict__ o1, __hip_bfloat16* __restrict__ o2,
                 int per)
{
    const int sel = blockIdx.x / per, rem = blockIdx.x % per;
    const float* in = sel == 0 ? i0 : (sel == 1 ? i1 : i2);
    __hip_bfloat16* out = sel == 0 ? o0 : (sel == 1 ? o1 : o2);
    const size_t i = ((size_t)rem * 256 + threadIdx.x) * 8;
    float4 a = *(const float4*)(in + i);
    float4 b = *(const float4*)(in + i + 4);
    short s[8] = { bf16bits(a.x), bf16bits(a.y), bf16bits(a.z), bf16bits(a.w),
                   bf16bits(b.x), bf16bits(b.y), bf16bits(b.z), bf16bits(b.w) };
    *(uint4*)(out + i) = *(const uint4*)s;
}

// ---------------------------------------------------------------------------
// m97-structure MFMA GEMM bits shared by gemm_qkv / gemm_mfma.
// ---------------------------------------------------------------------------
#define BKg 32

__device__ inline void async16(const __hip_bfloat16* g, short* l) {
    __builtin_amdgcn_global_load_lds(
        (const __attribute__((address_space(1))) void*)g,
        (__attribute__((address_space(3))) void*)l, 16, 0, 0);
}

// ---------------------------------------------------------------------------
// Merged QKV GEMM: one dispatch, 1536 blocks (3x 512) -> ~6 blocks/CU capacity
// nsel = blockIdx.x>>4 selects weight + output: 0->q, 1->k, 2->vt(transposed).
// ---------------------------------------------------------------------------
__global__ __launch_bounds__(256)
void gemm_qkv(const __hip_bfloat16* __restrict__ A,
              const __hip_bfloat16* __restrict__ wq,
              const __hip_bfloat16* __restrict__ wk,
              const __hip_bfloat16* __restrict__ wv,
              __hip_bfloat16* __restrict__ q,
              __hip_bfloat16* __restrict__ k,
              __hip_bfloat16* __restrict__ vt)
{
    __shared__ __align__(16) short sA[128 * BKg];
    __shared__ __align__(16) short sB[128 * BKg];

    const int tid  = threadIdx.x;
    const int w    = tid >> 6;
    const int lane = tid & 63;
    const int l15  = lane & 15;
    const int quad = lane >> 4;

    const int nsel = (int)blockIdx.x >> 4;          // 0:q 1:k 2:v
    const int n0   = ((int)blockIdx.x & 15) * 128;  // within [0, 2048)
    const int m0   = (int)blockIdx.y * 128;
    const __hip_bfloat16* W = nsel == 0 ? wq : (nsel == 1 ? wk : wv);

    const int sr0  = w * 32 + (lane >> 2);
    const int scol = (lane & 3) * 8;
    const int wm = (w >> 1) * 64;
    const int wn = (w & 1) * 64;

    f32x4 acc[4][4];
    #pragma unroll
    for (int i = 0; i < 4; i++)
        #pragma unroll
        for (int j = 0; j < 4; j++) acc[i][j] = (f32x4)(0.0f);

    for (int k0 = 0; k0 < D_; k0 += BKg) {
        #pragma unroll
        for (int t = 0; t < 2; t++) {
            const int r = sr0 + t * 16;
            async16(A + (size_t)(m0 + r) * D_ + k0 + scol, sA + (w * 2 + t) * 512);
            async16(W + (size_t)(n0 + r) * D_ + k0 + scol, sB + (w * 2 + t) * 512);
        }
        __syncthreads();

        bf16x8 af[4], bf[4];
        #pragma unroll
        for (int i = 0; i < 4; i++)
            af[i] = *(const bf16x8*)(sA + (wm + i * 16 + l15) * BKg + quad * 8);
        #pragma unroll
        for (int j = 0; j < 4; j++)
            bf[j] = *(const bf16x8*)(sB + (wn + j * 16 + l15) * BKg + quad * 8);
        #pragma unroll
        for (int i = 0; i < 4; i++)
            #pragma unroll
            for (int j = 0; j < 4; j++)
                acc[i][j] = __builtin_amdgcn_mfma_f32_16x16x32_bf16(af[i], bf[j], acc[i][j], 0, 0, 0);
        __syncthreads();
    }

    __hip_bfloat16* out = nsel == 0 ? q : (nsel == 1 ? k : vt);
    #pragma unroll
    for (int i = 0; i < 4; i++) {
        #pragma unroll
        for (int r = 0; r < 4; r++) {
            const int m = m0 + wm + i * 16 + quad * 4 + r;
            const int b = m / S_, s = m % S_;
            #pragma unroll
            for (int j = 0; j < 4; j++) {
                const int n  = n0 + wn + j * 16 + l15;
                const int h  = n / DH_, dh = n % DH_;
                const size_t idx = (nsel == 2)
                    ? (((size_t)(b * H_ + h)) * DH_ + dh) * S_ + s
                    : (((size_t)(b * H_ + h)) * S_ + s) * DH_ + dh;
                out[idx] = __float2bfloat16(acc[i][j][r]);
            }
        }
    }
}

// ---------------------------------------------------------------------------
// Final projection GEMM: C[M,N] = A[M,K] * W[N,K]^T, bf16 in, fp32 out.
// ---------------------------------------------------------------------------
__global__ __launch_bounds__(256)
void gemm_mfma(const __hip_bfloat16* __restrict__ A,
               const __hip_bfloat16* __restrict__ W,
               float* __restrict__ out, int M, int N, int K)
{
    __shared__ __align__(16) short sA[128 * BKg];
    __shared__ __align__(16) short sB[128 * BKg];

    const int tid  = threadIdx.x;
    const int w    = tid >> 6;
    const int lane = tid & 63;
    const int l15  = lane & 15;
    const int quad = lane >> 4;

    const int m0 = blockIdx.y * 128;
    const int n0 = blockIdx.x * 128;

    const int sr0 = w * 32 + (lane >> 2);
    const int scol = (lane & 3) * 8;
    const int wm = (w >> 1) * 64;
    const int wn = (w & 1) * 64;

    f32x4 acc[4][4];
    #pragma unroll
    for (int i = 0; i < 4; i++)
        #pragma unroll
        for (int j = 0; j < 4; j++) acc[i][j] = (f32x4)(0.0f);

    for (int k0 = 0; k0 < K; k0 += BKg) {
        #pragma unroll
        for (int t = 0; t < 2; t++) {
            const int r = sr0 + t * 16;
            async16(A + (size_t)(m0 + r) * K + k0 + scol, sA + (w * 2 + t) * 512);
            async16(W + (size_t)(n0 + r) * K + k0 + scol, sB + (w * 2 + t) * 512);
        }
        __syncthreads();

        bf16x8 af[4], bf[4];
        #pragma unroll
        for (int i = 0; i < 4; i++)
            af[i] = *(const bf16x8*)(sA + (wm + i * 16 + l15) * BKg + quad * 8);
        #pragma unroll
        for (int j = 0; j < 4; j++)
            bf[j] = *(const bf16x8*)(sB + (wn + j * 16 + l15) * BKg + quad * 8);
        #pragma unroll
        for (int i = 0; i < 4; i++)
            #pragma unroll
            for (int j = 0; j < 4; j++)
                acc[i][j] = __builtin_amdgcn_mfma_f32_16x16x32_bf16(af[i], bf[j], acc[i][j], 0, 0, 0);
        __syncthreads();
    }

    #pragma unroll
    for (int i = 0; i < 4; i++) {
        #pragma unroll
        for (int r = 0; r < 4; r++) {
            const int m = m0 + wm + i * 16 + quad * 4 + r;
            #pragma unroll
            for (int j = 0; j < 4; j++) {
                const int n = n0 + wn + j * 16 + l15;
                out[(size_t)m * N + n] = acc[i][j][r];
            }
        }
    }
}

// ---------------------------------------------------------------------------
// RoPE on q AND k in one launch; cos/sin fp32 [S, DH].
// ---------------------------------------------------------------------------
__global__ __launch_bounds__(256)
void rope2_kernel(__hip_bfloat16* __restrict__ q, __hip_bfloat16* __restrict__ k,
                  const float* __restrict__ cos_, const float* __restrict__ sin_,
                  int per)
{
    const int sel = blockIdx.x / per, rem = blockIdx.x % per;
    __hip_bfloat16* base = sel == 0 ? q : k;
    const size_t i = (size_t)rem * blockDim.x + threadIdx.x;
    const int dh = (int)(i & 63);
    const size_t row = i >> 6;
    const int s = (int)(row % S_);
    __hip_bfloat16* p = base + row * DH_;

    const float x1 = __bfloat162float(p[dh]);
    const float x2 = __bfloat162float(p[dh + 64]);
    const float c1 = cos_[s * DH_ + dh];
    const float s1 = sin_[s * DH_ + dh];
    const float c2 = cos_[s * DH_ + dh + 64];
    const float s2 = sin_[s * DH_ + dh + 64];

    p[dh]      = __float2bfloat16(x1 * c1 - x2 * s1);
    p[dh + 64] = __float2bfloat16(x2 * c2 + x1 * s2);
}

// ---------------------------------------------------------------------------
// Flash attention v4: 64-row q-tiles (4 waves x 16 rows), kv-tile 64.
//
// Spill history (rocprof): v3-v3.2 reg-staged kreg/vreg prefetch (32 VGPR
// live across barrier+compute) was spilled by the allocator every iter
// regardless of waves_per_eu / launch_bounds hints -> 490 MB scratch
// writes, 200 us. Fix is structural: prefetch via global_load_lds DMA
// (zero VGPR) into a double-buffered LDS, 2-phase schedule like the GEMMs
// (issue next-tile DMA -> compute current -> __syncthreads drains vmcnt).
//
// global_load_lds writes linearly (wave-uniform base + lane*16B), so the
// bank-conflict pads (KSTR/VSTR) are replaced by an XOR swizzle applied on
// BOTH sides (rule 21): per-lane pre-swizzled global source address at
// stage time, same XOR on the ds_read_b128 index at compute time.
//   K tile [64][128] bf16: granule byte col ^= (row&7)<<4  (2-way conflicts)
//   V tile [128][64] bf16: same XOR (rows are 128 B)
// LDS: 2x16K (K) + 2x16K (V) + 9K (P) = 73 KB -> 2 blocks/CU; 1024 blocks
// launched longest-first (LPT backfill).
// ---------------------------------------------------------------------------
#define PSTR 72

__global__ __launch_bounds__(256)
void attn_mfma(const __hip_bfloat16* __restrict__ q,
               const __hip_bfloat16* __restrict__ k,
               const __hip_bfloat16* __restrict__ vt,
               __hip_bfloat16* __restrict__ vals)
{
    __shared__ __align__(16) short sK[2 * 64 * 128];
    __shared__ __align__(16) short sV[2 * 128 * 64];
    __shared__ __align__(16) short sP[4 * 16 * PSTR];

    // 1D grid, longest-first: rank 0 -> qtile 31 (32 kv iters)
    const int idx   = (int)blockIdx.x;
    const int bh    = idx & 31;           // B_*H_ = 32
    const int qtile = 31 - (idx >> 5);    // 32 qtiles of 64 rows
    const int q0    = qtile * 64;
    const int tid   = threadIdx.x;
    const int w     = tid >> 6;
    const int lane  = tid & 63;
    const int l15   = lane & 15;
    const int quad  = lane >> 4;
    const int qb    = q0 + w * 16;        // this wave's 16 q-rows

    bf16x8 qf[4];
    {
        const __hip_bfloat16* qrow =
            q + ((size_t)bh * S_ + qb + l15) * DH_ + quad * 8;
        #pragma unroll
        for (int c = 0; c < 4; c++)
            qf[c] = *(const bf16x8*)(qrow + c * 32);
    }

    f32x4 o[8];
    #pragma unroll
    for (int d = 0; d < 8; d++) o[d] = (f32x4)(0.0f);
    float mrow[4], lrow[4];
    #pragma unroll
    for (int r = 0; r < 4; r++) { mrow[r] = -1e30f; lrow[r] = 0.f; }

    const float scale = 0.08838834764831845f;
    const int niter = qtile + 1;

    // DMA staging: wave w stages chunks 4w..4w+3 of each tile (1 KB/chunk).
    // K chunk c: rows 4c+(lane>>4), 16B granule (lane&15) of a 256B row.
    // V chunk c: rows 8c+(lane>>3), 16B granule (lane&7)  of a 128B row.
    const int krow_in = lane >> 4, kgran = lane & 15;
    const int vrow_in = lane >> 3, vgran = lane & 7;

    auto stage = [&](int bsel, int kv0) {
        short* kb = sK + bsel * 8192;
        short* vb = sV + bsel * 8192;
        #pragma unroll
        for (int t = 0; t < 4; t++) {
            const int c    = w * 4 + t;
            const int krow = c * 4 + krow_in;
            const int kcol = (kgran * 16) ^ ((krow & 7) << 4);   // bytes
            async16(k + ((size_t)bh * S_ + kv0 + krow) * DH_ + (kcol >> 1),
                    kb + c * 512);
            const int vrow = c * 8 + vrow_in;
            const int vcol = (vgran * 16) ^ ((vrow & 7) << 4);   // bytes
            async16(vt + ((size_t)bh * DH_ + vrow) * S_ + kv0 + (vcol >> 1),
                    vb + c * 512);
        }
    };

    stage(0, 0);
    __syncthreads();   // compiler emits vmcnt(0) before barrier: DMA landed

    int buf = 0;
    for (int it = 0; it < niter; ++it) {
        const int kv0 = it * 64;

        if (it + 1 < niter) stage(buf ^ 1, kv0 + 64);

        const short* kb = sK + buf * 8192;
        const short* vb = sV + buf * 8192;
        const int xsw = (l15 & 7) << 3;   // XOR swizzle, short units

        // QK^T for this wave's 16 rows x 64 kv
        f32x4 s[4];
        #pragma unroll
        for (int n = 0; n < 4; n++) s[n] = (f32x4)(0.0f);
        #pragma unroll
        for (int n = 0; n < 4; n++) {
            const short* kp = kb + (n * 16 + l15) * 128;
            #pragma unroll
            for (int c = 0; c < 4; c++) {
                bf16x8 kf = *(const bf16x8*)(kp + ((quad * 8 + c * 32) ^ xsw));
                s[n] = __builtin_amdgcn_mfma_f32_16x16x32_bf16(qf[c], kf, s[n], 0, 0, 0);
            }
        }

        // softmax (online, deferred l-reduce)
        {
            const bool msk = (kv0 + 63 > qb);
            float sv[4][4];
            #pragma unroll
            for (int n = 0; n < 4; n++)
                #pragma unroll
                for (int r = 0; r < 4; r++) {
                    float x = s[n][r] * scale;
                    if (msk) {
                        const int kvg = kv0 + n * 16 + l15;
                        const int qg  = qb + quad * 4 + r;
                        if (kvg > qg) x = -1e30f;
                    }
                    sv[n][r] = x;
                }

            float alpha[4];
            #pragma unroll
            for (int r = 0; r < 4; r++) {
                float v = fmaxf(fmaxf(sv[0][r], sv[1][r]), fmaxf(sv[2][r], sv[3][r]));
                #pragma unroll
                for (int m2 = 8; m2; m2 >>= 1)
                    v = fmaxf(v, __shfl_xor(v, m2, 64));
                const float mn = fmaxf(mrow[r], v);
                alpha[r] = __expf(mrow[r] - mn);
                mrow[r] = mn;
            }
            #pragma unroll
            for (int r = 0; r < 4; r++) {
                float rs = 0.f;
                #pragma unroll
                for (int n = 0; n < 4; n++) {
                    const float p = __expf(sv[n][r] - mrow[r]);
                    sv[n][r] = p;
                    rs += p;
                }
                lrow[r] = lrow[r] * alpha[r] + rs;
            }
            #pragma unroll
            for (int d = 0; d < 8; d++)
                #pragma unroll
                for (int r = 0; r < 4; r++)
                    o[d][r] *= alpha[r];

            short* pb = &sP[(w * 16) * PSTR];
            #pragma unroll
            for (int n = 0; n < 4; n++)
                #pragma unroll
                for (int r = 0; r < 4; r++)
                    pb[(quad * 4 + r) * PSTR + n * 16 + l15] = bf16bits(sv[n][r]);
        }

        // PV
        #pragma unroll
        for (int c = 0; c < 2; c++) {
            bf16x8 pf = *(const bf16x8*)(&sP[(w * 16 + l15) * PSTR + c * 32 + quad * 8]);
            #pragma unroll
            for (int d = 0; d < 8; d++) {
                bf16x8 vf = *(const bf16x8*)(vb + (d * 16 + l15) * 64 +
                                             ((quad * 8 + c * 32) ^ xsw));
                o[d] = __builtin_amdgcn_mfma_f32_16x16x32_bf16(pf, vf, o[d], 0, 0, 0);
            }
        }
        __syncthreads();   // drains vmcnt (next stage) + lgkm; flips buffer
        buf ^= 1;
    }

    const int b = bh >> 4, h = bh & 15;
    #pragma unroll
    for (int r = 0; r < 4; r++) {
        float l = lrow[r];
        #pragma unroll
        for (int m2 = 8; m2; m2 >>= 1)
            l += __shfl_xor(l, m2, 64);
        const float inv = 1.0f / l;
        const int qg = qb + quad * 4 + r;
        #pragma unroll
        for (int d = 0; d < 8; d++) {
            const int col = d * 16 + l15;
            vals[(((size_t)b * S_ + qg) * H_ + h) * DH_ + col] =
                __float2bfloat16(o[d][r] * inv);
        }
    }
}

// ---------------------------------------------------------------------------
extern "C" void kernel_launch(void* const* d_in, const int* in_sizes, int n_in,
                              void* d_out, int out_size, void* d_ws, size_t ws_size,
                              hipStream_t stream)
{
    const float* x    = (const float*)d_in[0];
    const float* cos_ = (const float*)d_in[1];
    const float* sin_ = (const float*)d_in[2];
    const float* Wq   = (const float*)d_in[3];
    const float* Wk   = (const float*)d_in[4];
    const float* Wv   = (const float*)d_in[5];
    const float* Wo   = (const float*)d_in[6];
    float* out = (float*)d_out;

    const size_t NELEM = (size_t)B_ * S_ * D_;       // 8388608
    const size_t WELEM = (size_t)D_ * D_;            // 4194304

    // d_out scratch during QKV phase: 3 bf16 weights (25.2 MB <= 33.5 MB)
    __hip_bfloat16* wqb = (__hip_bfloat16*)d_out;
    __hip_bfloat16* wkb = wqb + WELEM;
    __hip_bfloat16* wvb = wkb + WELEM;
    // ws (67 MB): q,k,vt,vals. xb shares the vals region (dead before attn
    // writes vals); Wo-bf16 reuses q region (dead after attn).
    __hip_bfloat16* q    = (__hip_bfloat16*)d_ws;
    __hip_bfloat16* k    = q + NELEM;
    __hip_bfloat16* vt   = k + NELEM;
    __hip_bfloat16* vals = vt + NELEM;
    __hip_bfloat16* xb   = vals;
    __hip_bfloat16* wob  = q;

    const int M = B_ * S_, N = D_, K = D_;
    const int xcb = (int)(NELEM / (256 * 8));        // 4096 blocks
    const int wcb = (int)(WELEM / (256 * 8));        // 2048 blocks

    f2b_kernel<<<xcb, 256, 0, stream>>>(x, xb);
    f2b3_kernel<<<3 * wcb, 256, 0, stream>>>(Wq, Wk, Wv, wqb, wkb, wvb, wcb);

    gemm_qkv<<<dim3(3 * N / 128, M / 128), 256, 0, stream>>>(xb, wqb, wkb, wvb, q, k, vt);

    const int rope_blocks = B_ * H_ * S_ * 64 / 256;  // per tensor
    rope2_kernel<<<2 * rope_blocks, 256, 0, stream>>>(q, k, cos_, sin_, rope_blocks);

    // 32 qtiles x 32 bh, longest-first for LPT backfill
    attn_mfma<<<dim3(32 * (B_ * H_)), 256, 0, stream>>>(q, k, vt, vals);

    f2b_kernel<<<wcb, 256, 0, stream>>>(Wo, wob);
    gemm_mfma<<<dim3(N / 128, M / 128), 256, 0, stream>>>(vals, wob, out, M, N, K);
}